// Round 11
// baseline (1989.160 us; speedup 1.0000x reference)
//
#include <hip/hip_runtime.h>
#include <stdint.h>
#include <math.h>

// ---------------------------------------------------------------------------
// RSNN forward, MI355X. EXACT integer hidden GEMM (rounds 3-10, absmax
// 0.0156): 27-bit fixed-point weights -> 3 signed base-256 i8 digit planes,
// binary activations, i32 MFMA, exact int64 recombination, single fp32
// round, fp32 program-order decay.
// Round-11: persistent kernel, XCD-LOCAL recurrence. Batch rows are
// partitioned by PHYSICAL XCD (HW_REG_XCC_ID + atomic roster): all spike /
// o-partial producer-consumer traffic stays inside one XCD's L2, so plain
// cached accesses are coherent (no fences, no sc flags, no L2 flushes).
// Per-XCD monotonic barrier with RELAXED agent atomics only (r7's failure
// was acquire-ordered spins + threadfence flushing L2 every poll).
// Block = (xcd, slot): 32 batch rows (xcd) x 64 h (slot), full K; hidden
// membranes in VGPRs; weights stream from LLC (L2 never invalidated).
// ---------------------------------------------------------------------------

#define B_   256
#define T_   50
#define I_   1024
#define H_   2048
#define O_   20
#define XIN_T  262144    // input bytes per t: 4 bt * 16 kx * 4096
#define WNT 589824       // weight bytes per nt (64 cols): 3 * 48 * 4096
#define WPL 196608       // bytes per plane within an nt

typedef __attribute__((ext_vector_type(4))) int intx4;
typedef long long ll_t;

// ---------------------------------------------------------------------------
// Weight prep: digit p of W(n,kk) -> [nt 32][p 3][kx 48][row64 * 64B]
// ---------------------------------------------------------------------------
__device__ __forceinline__ int digit_of(float v, int p) {
  int W = (int)rintf(v * 134217728.0f);   // exact: |W| <= 2^22
  int c0 = ((W + 128) & 255) - 128;
  int W1 = (W - c0) >> 8;
  int c1 = ((W1 + 128) & 255) - 128;
  int W2 = (W1 - c1) >> 8;
  return (p == 0) ? c0 : (p == 1) ? c1 : W2;
}

__global__ void prep_w(const float* __restrict__ w_ih,
                       const float* __restrict__ w_hh,
                       int8_t* __restrict__ Wtl) {
  int blk = blockIdx.x;
  int n = blk / 9, kg = blk % 9;
  int k9 = (kg * 256 + (int)threadIdx.x) * 4;   // [0, 9216)
  int p = k9 / 3072, kk = k9 % 3072;
  const float* src = (kk < 1024) ? (w_ih + n * I_ + kk)
                                 : (w_hh + n * H_ + (kk - 1024));
  float4 v = *(const float4*)src;
  int d0 = digit_of(v.x, p) & 255;
  int d1 = digit_of(v.y, p) & 255;
  int d2 = digit_of(v.z, p) & 255;
  int d3 = digit_of(v.w, p) & 255;
  int packed = d0 | (d1 << 8) | (d2 << 16) | (d3 << 24);
  size_t off = (size_t)(n >> 6) * WNT + (size_t)p * WPL + (kk >> 6) * 4096 +
               (n & 63) * 64 + (kk & 63);
  *(int*)(Wtl + off) = packed;
}

// ---------------------------------------------------------------------------
// Init: pack input for ALL t, zero spike buffers, WhoD, control words.
// grid 256 x 256 = 65536 threads.
// ---------------------------------------------------------------------------
__global__ void init_k(int8_t* __restrict__ Xin, int8_t* __restrict__ Xs,
                       const float* __restrict__ input,
                       const float* __restrict__ w_ho, double* __restrict__ WhoD,
                       unsigned* __restrict__ Ctl) {
  int id = blockIdx.x * 256 + threadIdx.x;   // [0, 65536)
  {
    int b = id >> 8, i4 = (id & 255) * 4;
    for (int t = 0; t < T_; ++t) {
      float4 v = *(const float4*)(input + ((size_t)(b * T_ + t) << 10) + i4);
      uchar4 pk;
      pk.x = v.x > 0.5f ? 1 : 0;
      pk.y = v.y > 0.5f ? 1 : 0;
      pk.z = v.z > 0.5f ? 1 : 0;
      pk.w = v.w > 0.5f ? 1 : 0;
      *(uchar4*)(Xin + (size_t)t * XIN_T + (b >> 6) * 65536 + (i4 >> 6) * 4096 +
                 (b & 63) * 64 + (i4 & 63)) = pk;
    }
  }
  *(float4*)(Xs + (size_t)id * 16) = make_float4(0.f, 0.f, 0.f, 0.f);  // 1 MB
  if (id < 32 * O_ * 64) {                      // WhoD [slot 32][o 20][hl 64]
    int nt = id / 1280, rem = id % 1280, o = rem / 64, hl = rem & 63;
    WhoD[id] = (double)w_ho[o * H_ + nt * 64 + hl];
  }
  if (id < 24) Ctl[id] = 0u;   // [0..7] roster, [8..15] arrive, [16..23] release
}

// ---------------------------------------------------------------------------
// Persistent kernel: 256 blocks x 512 threads (1 block/CU forced by VGPR).
// Block (xcd, slot): batch rows xcd*32..+32, h cols slot*64..+64, full K.
// Waves: (c = h-half) x (k = K-quarter, 12 slabs). A-slabs: u<16 input,
// u>=16 spikes (XCD-local buffer, parity t&1).
// ---------------------------------------------------------------------------
__global__ __launch_bounds__(512, 2) void rsnn_pers(
    const int8_t* __restrict__ Wtl, const int8_t* __restrict__ Xin,
    int8_t* __restrict__ Xs, double* __restrict__ Po,
    const double* __restrict__ WhoD, const float* __restrict__ tau_h,
    const float* __restrict__ tau_o, unsigned* __restrict__ Ctl,
    float* __restrict__ out) {
  __shared__ double WhoL[1280];
  __shared__ __align__(16) int8_t red[49152];
  __shared__ int8_t spk_lT[2048];   // [col 64][row 32]
  __shared__ float om_l[O_];
  __shared__ unsigned binfo[2];

  const int tid = threadIdx.x;
  if (tid == 0) {
    unsigned xcc;
    asm volatile("s_getreg_b32 %0, hwreg(HW_REG_XCC_ID)" : "=s"(xcc));
    xcc &= 7u;
    unsigned slot = __hip_atomic_fetch_add(&Ctl[xcc], 1u, __ATOMIC_RELAXED,
                                           __HIP_MEMORY_SCOPE_AGENT);
    binfo[0] = xcc;
    binfo[1] = slot & 31u;
  }
  __syncthreads();
  const int xcd = (int)binfo[0], slot = (int)binfo[1];

  const int l = tid & 63, wv = tid >> 6;
  const int c = wv >> 2, k = wv & 3;
  const int r_ = l & 15, q = l >> 4;
  const int bg = xcd;

  for (int i = tid; i < 1280; i += 512) WhoL[i] = WhoD[slot * 1280 + i];

  // per-lane constants / persistent state
  float alphaO_r = 0.f;
  if (tid < O_) {
    float rr = -1.0f / tau_o[tid];
    alphaO_r = (float)exp((double)rr);
  }
  float Om_r = 0.f, Osu_r = 0.f, Mo_r = 0.f;
  float alpha_f[2];
#pragma unroll
  for (int fc = 0; fc < 2; ++fc) {
    int h = slot * 64 + c * 32 + fc * 16 + r_;
    float rr = -1.0f / tau_h[h];
    alpha_f[fc] = (float)exp((double)rr);
  }
  float hm_r[2][2][4];   // [fc][fr][jj], waves k==0 only
#pragma unroll
  for (int fc = 0; fc < 2; ++fc)
#pragma unroll
    for (int fr = 0; fr < 2; ++fr)
#pragma unroll
      for (int jj = 0; jj < 4; ++jj) hm_r[fc][fr][jj] = 0.f;

  const int arow_in = ((bg & 1) * 32 + r_) * 64 + q * 16;
  const int arow_sp = r_ * 64 + q * 16;
  const int8_t* AinB = Xin + (bg >> 1) * 65536 + arow_in;
  int8_t* XsX = Xs + xcd * 131072;
  const int8_t* Bw = Wtl + (size_t)slot * WNT + (c * 32 + r_) * 64 + q * 16;
  const int u0 = k * 12;
  const int brow = xcd * 32 + slot;   // this block's o-phase batch row

  for (int t = 0; t < T_; ++t) {
    // ---- wait for step t-1 (XCD-local), then o-phase(t-1) ----
    if (t > 0) {
      if (tid == 0) {
        unsigned v;
        do {
          __builtin_amdgcn_s_sleep(2);
          v = __hip_atomic_load(&Ctl[16 + xcd], __ATOMIC_RELAXED,
                                __HIP_MEMORY_SCOPE_AGENT);
        } while (v < (unsigned)t);
      }
      __syncthreads();
      const int par = (t - 1) & 1;
      if (tid < O_) {
        const double* pp =
            Po + ((((size_t)xcd * 2 + par) * 32) * 32 + slot) * 20 + tid;
        double s = 0.0;
#pragma unroll
        for (int s2 = 0; s2 < 32; ++s2) s += pp[(size_t)s2 * 640];
        float r = (float)s;
        float spo = (Om_r - 0.3f) > 0.f ? 1.f : 0.f;
        float m = Om_r * alphaO_r * (1.0f - spo) + r;
        om_l[tid] = m;
      }
      __syncthreads();
      if (tid < O_) {
        float m = om_l[tid];
        float mx = om_l[0];
#pragma unroll
        for (int o = 1; o < O_; ++o) mx = fmaxf(mx, om_l[o]);
        float se = 0.f;
#pragma unroll
        for (int o = 0; o < O_; ++o) se += expf(om_l[o] - mx);
        float sp = (m - 0.3f) > 0.f ? 1.f : 0.f;
        Om_r = m;
        Osu_r += sp;
        Mo_r += expf(m - mx) / se;
      }
      __syncthreads();
    }

    // ---- K-loop: 12 slabs/wave, depth-1 rotation, no barriers ----
    const int8_t* Ain = AinB + (size_t)t * XIN_T;
    const int8_t* Asp = XsX + (t & 1) * 65536 + arow_sp;

    intx4 acc[2][2][3];   // [fr][fc][p]
#pragma unroll
    for (int fr = 0; fr < 2; ++fr)
#pragma unroll
      for (int fc = 0; fc < 2; ++fc)
#pragma unroll
        for (int p = 0; p < 3; ++p) acc[fr][fc][p] = (intx4){0, 0, 0, 0};

    intx4 a[2][2], b[2][2][3];
    {
      const int8_t* ap = (u0 < 16) ? (Ain + u0 * 4096) : (Asp + (u0 - 16) * 2048);
      a[0][0] = *(const intx4*)ap;
      a[0][1] = *(const intx4*)(ap + 1024);
      const int8_t* bp = Bw + u0 * 4096;
#pragma unroll
      for (int p = 0; p < 3; ++p)
#pragma unroll
        for (int fc = 0; fc < 2; ++fc)
          b[0][fc][p] = *(const intx4*)(bp + p * WPL + fc * 1024);
    }
#pragma unroll
    for (int i = 0; i < 12; ++i) {
      const int cur = i & 1, nxt = cur ^ 1;
      if (i < 11) {
        const int un = u0 + i + 1;
        const int8_t* ap =
            (un < 16) ? (Ain + un * 4096) : (Asp + (un - 16) * 2048);
        a[nxt][0] = *(const intx4*)ap;
        a[nxt][1] = *(const intx4*)(ap + 1024);
        const int8_t* bp = Bw + un * 4096;
#pragma unroll
        for (int p = 0; p < 3; ++p)
#pragma unroll
          for (int fc = 0; fc < 2; ++fc)
            b[nxt][fc][p] = *(const intx4*)(bp + p * WPL + fc * 1024);
      }
#pragma unroll
      for (int p = 0; p < 3; ++p)
#pragma unroll
        for (int fc = 0; fc < 2; ++fc) {
          acc[0][fc][p] = __builtin_amdgcn_mfma_i32_16x16x64_i8(
              a[cur][0], b[cur][fc][p], acc[0][fc][p], 0, 0, 0);
          acc[1][fc][p] = __builtin_amdgcn_mfma_i32_16x16x64_i8(
              a[cur][1], b[cur][fc][p], acc[1][fc][p], 0, 0, 0);
        }
    }

    // ---- exact K-quarter merge: pairwise i32 LDS tree (r9) ----
#define REDP(s, idx) (red + (((c * 2 + (s)) * 12 + (idx)) * 64 + l) * 16)
#define ACCIDX(fr, fc, p) ((fr) * 6 + (fc) * 3 + (p))
    if (k == 1 || k == 3) {
      const int s = k >> 1;
#pragma unroll
      for (int fr = 0; fr < 2; ++fr)
#pragma unroll
        for (int fc = 0; fc < 2; ++fc)
#pragma unroll
          for (int p = 0; p < 3; ++p)
            *(intx4*)REDP(s, ACCIDX(fr, fc, p)) = acc[fr][fc][p];
    }
    __syncthreads();
    if (k == 0 || k == 2) {
      const int s = k >> 1;
#pragma unroll
      for (int fr = 0; fr < 2; ++fr)
#pragma unroll
        for (int fc = 0; fc < 2; ++fc)
#pragma unroll
          for (int p = 0; p < 3; ++p)
            acc[fr][fc][p] =
                acc[fr][fc][p] + *(const intx4*)REDP(s, ACCIDX(fr, fc, p));
      if (k == 2) {
#pragma unroll
        for (int fr = 0; fr < 2; ++fr)
#pragma unroll
          for (int fc = 0; fc < 2; ++fc)
#pragma unroll
            for (int p = 0; p < 3; ++p)
              *(intx4*)REDP(1, ACCIDX(fr, fc, p)) = acc[fr][fc][p];
      }
    }
    __syncthreads();

    // ---- hidden epilogue (waves k==0): decay, spike, stores ----
    if (k == 0) {
      int8_t* Xw = XsX + ((t + 1) & 1) * 65536 + slot * 2048;
#pragma unroll
      for (int fc = 0; fc < 2; ++fc) {
        const int hcol = c * 32 + fc * 16 + r_;   // in-slab byte
#pragma unroll
        for (int fr = 0; fr < 2; ++fr) {
          intx4 s0 = acc[fr][fc][0] + *(const intx4*)REDP(1, ACCIDX(fr, fc, 0));
          intx4 s1 = acc[fr][fc][1] + *(const intx4*)REDP(1, ACCIDX(fr, fc, 1));
          intx4 s2 = acc[fr][fc][2] + *(const intx4*)REDP(1, ACCIDX(fr, fc, 2));
          unsigned spkpack = 0;
#pragma unroll
          for (int jj = 0; jj < 4; ++jj) {
            ll_t Sv = (ll_t)s0[jj] + ((ll_t)s1[jj] << 8) + ((ll_t)s2[jj] << 16);
            float M = (float)((double)Sv * 7.450580596923828125e-9);  // 2^-27
            float hp = hm_r[fc][fr][jj];
            float spf = (hp - 0.3f) > 0.f ? 1.f : 0.f;
            float hm = M + hp * alpha_f[fc] * (1.0f - spf);  // fp32 order
            hm_r[fc][fr][jj] = hm;
            unsigned spk = (hm - 0.3f) > 0.f ? 1u : 0u;
            int row = fr * 16 + q * 4 + jj;       // local batch row 0..31
            Xw[row * 64 + hcol] = (int8_t)spk;
            spkpack |= spk << (8 * jj);
          }
          *(unsigned*)(spk_lT + (c * 32 + fc * 16 + r_) * 32 + fr * 16 + q * 4) =
              spkpack;
        }
      }
    }
    __syncthreads();

    // ---- o-partials: 64-h double dot -> Po[xcd][t&1][slot][bl][og] ----
    if (tid < 128) {
      const int bl = tid >> 2, og = (tid & 3) * 5;
      const double* W0 = WhoL + og * 64;
      double a0 = 0, a1 = 0, a2 = 0, a3 = 0, a4 = 0;
#pragma unroll
      for (int hl = 0; hl < 64; ++hl) {
        double m = (double)spk_lT[hl * 32 + bl];
        a0 += m * W0[hl];
        a1 += m * W0[64 + hl];
        a2 += m * W0[128 + hl];
        a3 += m * W0[192 + hl];
        a4 += m * W0[256 + hl];
      }
      double* dst =
          Po + ((((size_t)xcd * 2 + (t & 1)) * 32 + slot) * 32 + bl) * 20 + og;
      dst[0] = a0; dst[1] = a1; dst[2] = a2; dst[3] = a3; dst[4] = a4;
    }
#undef REDP
#undef ACCIDX

    // ---- arrive (XCD-local, relaxed atomics only) ----
    __builtin_amdgcn_s_waitcnt(0);
    __syncthreads();
    if (tid == 0) {
      unsigned old = __hip_atomic_fetch_add(&Ctl[8 + xcd], 1u, __ATOMIC_RELAXED,
                                            __HIP_MEMORY_SCOPE_AGENT);
      if (old == (unsigned)(32 * (t + 1) - 1))
        __hip_atomic_store(&Ctl[16 + xcd], (unsigned)(t + 1), __ATOMIC_RELAXED,
                           __HIP_MEMORY_SCOPE_AGENT);
    }
  }

  // ---- final o-phase (t=49) + output ----
  if (tid == 0) {
    unsigned v;
    do {
      __builtin_amdgcn_s_sleep(2);
      v = __hip_atomic_load(&Ctl[16 + xcd], __ATOMIC_RELAXED,
                            __HIP_MEMORY_SCOPE_AGENT);
    } while (v < (unsigned)T_);
  }
  __syncthreads();
  {
    const int par = (T_ - 1) & 1;
    if (tid < O_) {
      const double* pp =
          Po + ((((size_t)xcd * 2 + par) * 32) * 32 + slot) * 20 + tid;
      double s = 0.0;
#pragma unroll
      for (int s2 = 0; s2 < 32; ++s2) s += pp[(size_t)s2 * 640];
      float r = (float)s;
      float spo = (Om_r - 0.3f) > 0.f ? 1.f : 0.f;
      float m = Om_r * alphaO_r * (1.0f - spo) + r;
      om_l[tid] = m;
    }
    __syncthreads();
    if (tid < O_) {
      float m = om_l[tid];
      float mx = om_l[0];
#pragma unroll
      for (int o = 1; o < O_; ++o) mx = fmaxf(mx, om_l[o]);
      float se = 0.f;
#pragma unroll
      for (int o = 0; o < O_; ++o) se += expf(om_l[o] - mx);
      float sp = (m - 0.3f) > 0.f ? 1.f : 0.f;
      out[brow * O_ + tid] = (Osu_r + sp) / 50.0f;
      out[B_ * O_ + brow * O_ + tid] = Mo_r + expf(m - mx) / se;
    }
  }
}

// ---------------------------------------------------------------------------
extern "C" void kernel_launch(void* const* d_in, const int* in_sizes, int n_in,
                              void* d_out, int out_size, void* d_ws, size_t ws_size,
                              hipStream_t stream) {
  const float* input = (const float*)d_in[0];
  const float* w_ih  = (const float*)d_in[1];
  const float* w_hh  = (const float*)d_in[2];
  const float* w_ho  = (const float*)d_in[3];
  const float* tau_h = (const float*)d_in[4];
  const float* tau_o = (const float*)d_in[5];

  char* ws = (char*)d_ws;
  // layout (bytes):
  // Wtl  @ 0          18,874,368
  // Xin  @ 18874368   13,107,200
  // Xs   @ 31981568    1,048,576   ([xcd 8][par 2][kx 32][row 32][64B])
  // Po   @ 33030144    6,553,600   ([xcd 8][par 2][slot 32][row 32][o 20] f64)
  // WhoD @ 39583744      327,680
  // Ctl  @ 39911424           96
  int8_t*   Wtl  = (int8_t*)(ws);
  int8_t*   Xin  = (int8_t*)(ws + 18874368);
  int8_t*   Xs   = (int8_t*)(ws + 31981568);
  double*   Po   = (double*)(ws + 33030144);
  double*   WhoD = (double*)(ws + 39583744);
  unsigned* Ctl  = (unsigned*)(ws + 39911424);
  float*    out  = (float*)d_out;

  prep_w<<<2048 * 9, 256, 0, stream>>>(w_ih, w_hh, Wtl);
  init_k<<<256, 256, 0, stream>>>(Xin, Xs, input, w_ho, WhoD, Ctl);
  rsnn_pers<<<256, 512, 0, stream>>>(Wtl, Xin, Xs, Po, WhoD, tau_h, tau_o,
                                     Ctl, out);
}